// Round 1
// baseline (1057.785 us; speedup 1.0000x reference)
//
#include <hip/hip_runtime.h>
#include <hip/hip_bf16.h>
#include <stdint.h>

#define T_TOK   16384
#define INF     4096
#define OUTF    4096
#define NEXP    64
#define TOPK    16
#define RDIM    16
#define BOT     512

typedef float  f32x4  __attribute__((ext_vector_type(4)));
typedef short  bf16x8 __attribute__((ext_vector_type(8)));

__device__ __forceinline__ unsigned short f2bf(float f) {
    union { float f; unsigned int u; } c; c.f = f;
    unsigned int r = c.u + 0x7fffu + ((c.u >> 16) & 1u);
    return (unsigned short)(r >> 16);
}

// async global->LDS, 16B per lane. LDS dest must be wave-uniform base + lane*16.
// int-cast chain avoids addrspace-cast diagnostics; low 32 bits of a generic
// LDS pointer are the LDS offset (CK-style truncation).
__device__ __forceinline__ void gld_lds16(const void* g, void* l) {
    __builtin_amdgcn_global_load_lds(
        (const __attribute__((address_space(1))) unsigned int*)(uintptr_t)g,
        (__attribute__((address_space(3))) unsigned int*)(unsigned int)(uintptr_t)l,
        16, 0, 0);
}

// ---------------- weight cast: A_w (512x4096) + B_w (4096x512) fp32 -> bf16 ----
__global__ void __launch_bounds__(256) cast_w(const float* __restrict__ A,
                                              const float* __restrict__ B,
                                              unsigned short* __restrict__ Ab,
                                              unsigned short* __restrict__ Bb) {
    int i = blockIdx.x * 256 + threadIdx.x;
    const int nA = (BOT * INF) / 4;
    const float* src; unsigned short* dst; int k;
    if (i < nA) { src = A; dst = Ab; k = i; }
    else        { src = B; dst = Bb; k = i - nA; }
    f32x4 v = ((const f32x4*)src)[k];
    ushort4 o;
    o.x = f2bf(v.x); o.y = f2bf(v.y); o.z = f2bf(v.z); o.w = f2bf(v.w);
    ((ushort4*)dst)[k] = o;
}

// ---------------- router: q = x@Wq^T (fp32), topk+softmax -> gate; cast x->bf16
#define RT_TPB    32      // tokens per block
#define RT_CHUNK  1024    // d-chunk staged in LDS
#define RT_NCHUNK (INF / RT_CHUNK)

__global__ void __launch_bounds__(256) router_kernel(
    const float* __restrict__ x,      // [T][4096]
    const float* __restrict__ Wq,     // [16][4096]
    const float* __restrict__ keys,   // [64][16]
    unsigned short* __restrict__ xb,  // [T][4096] bf16 out
    float* __restrict__ gate)         // [T][64] out
{
    __shared__ float wq_s[RDIM][RT_CHUNK];   // 64 KB
    __shared__ float q_s[RT_TPB][RDIM];      // 2 KB

    const int tid  = threadIdx.x;
    const int lane = tid & 63;
    const int wave = tid >> 6;
    const int t0   = blockIdx.x * RT_TPB;
    const int ntok = RT_TPB / 4;             // 8 tokens per wave

    // keys row for this lane's expert, kept in registers
    f32x4 kreg[4];
    #pragma unroll
    for (int i = 0; i < 4; ++i)
        kreg[i] = *(const f32x4*)&keys[lane * RDIM + i * 4];

    for (int i = tid; i < RT_TPB * RDIM; i += 256)
        ((float*)q_s)[i] = 0.0f;

    for (int c = 0; c < RT_NCHUNK; ++c) {
        __syncthreads();
        // stage Wq chunk [16][1024]
        for (int i = tid; i < RDIM * RT_CHUNK / 4; i += 256) {
            int r  = i / (RT_CHUNK / 4);
            int d4 = i - r * (RT_CHUNK / 4);
            ((f32x4*)&wq_s[r][0])[d4] = ((const f32x4*)&Wq[(size_t)r * INF + c * RT_CHUNK])[d4];
        }
        __syncthreads();

        // prefetch token 0's x chunk
        f32x4 xn[4];
        {
            int t = t0 + wave * ntok;
            const f32x4* xp = (const f32x4*)&x[(size_t)t * INF + c * RT_CHUNK];
            #pragma unroll
            for (int j = 0; j < 4; ++j) xn[j] = xp[j * 64 + lane];
        }
        for (int it = 0; it < ntok; ++it) {
            int t = t0 + wave * ntok + it;
            f32x4 xv[4];
            #pragma unroll
            for (int j = 0; j < 4; ++j) xv[j] = xn[j];
            if (it + 1 < ntok) {
                const f32x4* xp = (const f32x4*)&x[(size_t)(t + 1) * INF + c * RT_CHUNK];
                #pragma unroll
                for (int j = 0; j < 4; ++j) xn[j] = xp[j * 64 + lane];
            }
            // cast+store bf16 (coalesced 8B/lane)
            #pragma unroll
            for (int j = 0; j < 4; ++j) {
                ushort4 bv;
                bv.x = f2bf(xv[j].x); bv.y = f2bf(xv[j].y);
                bv.z = f2bf(xv[j].z); bv.w = f2bf(xv[j].w);
                *(ushort4*)&xb[(size_t)t * INF + c * RT_CHUNK + j * 256 + lane * 4] = bv;
            }
            float acc[RDIM];
            #pragma unroll
            for (int r = 0; r < RDIM; ++r) acc[r] = 0.0f;
            #pragma unroll
            for (int j = 0; j < 4; ++j) {
                int d = j * 256 + lane * 4;
                #pragma unroll
                for (int r = 0; r < RDIM; ++r) {
                    f32x4 wv = *(const f32x4*)&wq_s[r][d];
                    acc[r] += xv[j].x * wv.x + xv[j].y * wv.y
                            + xv[j].z * wv.z + xv[j].w * wv.w;
                }
            }
            // wave tree-reduce each q_r
            #pragma unroll
            for (int r = 0; r < RDIM; ++r) {
                float v = acc[r];
                #pragma unroll
                for (int off = 32; off > 0; off >>= 1)
                    v += __shfl_xor(v, off, 64);
                if (lane == 0) q_s[wave * ntok + it][r] += v;
            }
        }
    }
    __syncthreads();

    // top-k + softmax, lane = expert
    for (int it = 0; it < ntok; ++it) {
        int tl = wave * ntok + it;
        int t  = t0 + tl;
        float s = 0.0f;
        #pragma unroll
        for (int i = 0; i < 4; ++i) {
            s += q_s[tl][i*4+0] * kreg[i].x + q_s[tl][i*4+1] * kreg[i].y
               + q_s[tl][i*4+2] * kreg[i].z + q_s[tl][i*4+3] * kreg[i].w;
        }
        // rank = #experts strictly better (value desc, index asc) -> exact top_k semantics
        int rank = 0;
        for (int j = 0; j < 64; ++j) {
            float sj = __shfl(s, j, 64);
            rank += (sj > s || (sj == s && j < lane)) ? 1 : 0;
        }
        float m = s;
        #pragma unroll
        for (int off = 32; off > 0; off >>= 1)
            m = fmaxf(m, __shfl_xor(m, off, 64));
        float e = (rank < TOPK) ? __expf(s - m) : 0.0f;
        float sum = e;
        #pragma unroll
        for (int off = 32; off > 0; off >>= 1)
            sum += __shfl_xor(sum, off, 64);
        gate[(size_t)t * NEXP + lane] = e / sum;
    }
}

// ---------------- m97-style bf16 B^T GEMM: C[M,N] = A[M,K] * B[N,K]^T --------
// EPI 0: C -> bf16 Zg with per-(row,expert) gate.  EPI 1: C -> fp32 out * 2.0
template <int EPI>
__global__ void __launch_bounds__(256) gemm_bt(
    const unsigned short* __restrict__ A,
    const unsigned short* __restrict__ Bm,
    const float* __restrict__ gate,
    unsigned short* __restrict__ Cb,
    float* __restrict__ Cf,
    const int M, const int N, const int K)
{
    constexpr int BM = 128, BN = 128, BK = 32;
    __shared__ __align__(16) unsigned short As[BM * BK];   // 8 KB
    __shared__ __align__(16) unsigned short Bs[BN * BK];   // 8 KB

    const int tid  = threadIdx.x;
    const int lane = tid & 63;
    const int wave = tid >> 6;
    const int wr = wave >> 1, wc = wave & 1;
    const int bm = blockIdx.y * BM;
    const int bn = blockIdx.x * BN;

    f32x4 acc[4][4] = {};

    // staging: thread stages 16B: row tid/4 (+64 for 2nd issue), col (tid%4)*8 elems
    const int srow = tid >> 2;
    const int scol = (tid & 3) * 8;
    const unsigned short* Ap = A  + (size_t)(bm + srow) * K + scol;
    const unsigned short* Bp = Bm + (size_t)(bn + srow) * K + scol;
    unsigned short* AsP = &As[tid * 8];   // == wave-uniform base + lane*16B
    unsigned short* BsP = &Bs[tid * 8];

    const int fm = lane & 15;
    const int fk = (lane >> 4) * 8;

    for (int k0 = 0; k0 < K; k0 += BK) {
        __syncthreads();
        gld_lds16(Ap,                 AsP);
        gld_lds16(Ap + (size_t)64 * K, AsP + 64 * BK);
        gld_lds16(Bp,                 BsP);
        gld_lds16(Bp + (size_t)64 * K, BsP + 64 * BK);
        Ap += BK; Bp += BK;
        __syncthreads();

        bf16x8 af[4], bfr[4];
        #pragma unroll
        for (int i = 0; i < 4; ++i)
            af[i] = *(const bf16x8*)&As[(wr * 64 + i * 16 + fm) * BK + fk];
        #pragma unroll
        for (int j = 0; j < 4; ++j)
            bfr[j] = *(const bf16x8*)&Bs[(wc * 64 + j * 16 + fm) * BK + fk];
        #pragma unroll
        for (int i = 0; i < 4; ++i)
            #pragma unroll
            for (int j = 0; j < 4; ++j)
                acc[i][j] = __builtin_amdgcn_mfma_f32_16x16x32_bf16(af[i], bfr[j], acc[i][j], 0, 0, 0);
    }

    // epilogue: C/D layout col=lane&15, row=(lane>>4)*4+reg  (m89/m91-verified)
    const int row0 = (lane >> 4) * 4;
    const int col  = lane & 15;
    #pragma unroll
    for (int i = 0; i < 4; ++i) {
        #pragma unroll
        for (int j = 0; j < 4; ++j) {
            const int nn = bn + wc * 64 + j * 16 + col;
            #pragma unroll
            for (int r = 0; r < 4; ++r) {
                const int mm = bm + wr * 64 + i * 16 + row0 + r;
                if (EPI == 0) {
                    float g = gate[(size_t)mm * NEXP + (nn >> 3)];
                    Cb[(size_t)mm * N + nn] = f2bf(acc[i][j][r] * g);
                } else {
                    Cf[(size_t)mm * N + nn] = acc[i][j][r] * 2.0f;
                }
            }
        }
    }
}

extern "C" void kernel_launch(void* const* d_in, const int* in_sizes, int n_in,
                              void* d_out, int out_size, void* d_ws, size_t ws_size,
                              hipStream_t stream) {
    const float* x    = (const float*)d_in[0];
    const float* A_w  = (const float*)d_in[1];
    const float* B_w  = (const float*)d_in[2];
    const float* Wq   = (const float*)d_in[3];
    const float* keys = (const float*)d_in[4];
    float* out = (float*)d_out;

    char* ws = (char*)d_ws;
    unsigned short* xb = (unsigned short*)(ws);                       // 134217728 B
    unsigned short* Ab = (unsigned short*)(ws + 134217728);           //   4194304 B
    unsigned short* Bb = (unsigned short*)(ws + 138412032);           //   4194304 B
    float*        gate = (float*)        (ws + 142606336);            //   4194304 B
    unsigned short* Zg = (unsigned short*)(ws + 146800640);           //  16777216 B
    // total ws use: 163,577,856 B

    cast_w<<<dim3(4096), dim3(256), 0, stream>>>(A_w, B_w, Ab, Bb);
    router_kernel<<<dim3(T_TOK / RT_TPB), dim3(256), 0, stream>>>(x, Wq, keys, xb, gate);
    gemm_bt<0><<<dim3(BOT / 128, T_TOK / 128), dim3(256), 0, stream>>>(
        xb, Ab, gate, Zg, nullptr, T_TOK, BOT, INF);
    gemm_bt<1><<<dim3(OUTF / 128, T_TOK / 128), dim3(256), 0, stream>>>(
        Zg, Bb, nullptr, nullptr, out, T_TOK, OUTF, BOT);
}